// Round 5
// baseline (44.138 us; speedup 1.0000x reference)
//
#include <hip/hip_runtime.h>

#define MU_STEP (30.0f / 63.0f)
#define LN2F 0.69314718055994531f

static __device__ __forceinline__ float ssp(float x) {
    // softplus(x) - ln2, stable: max(x,0) + log(1+exp(-|x|)) - ln2
    return fmaxf(x, 0.f) + __logf(1.f + __expf(-fabsf(x))) - LN2F;
}

// Build TD[k][g] = { T[k][g], T[k+1][g]-T[k][g] } (float2, row=1KB), where
// T[k][g] = ssp(ssp(rbf(k*hstep)@W1+b1)@W2+b2)[g]. Each block computes 5
// consecutive T rows in LDS and emits 4 TD rows.
__global__ __launch_bounds__(256, 4)
void build_td(const float* __restrict__ W1, const float* __restrict__ b1,
              const float* __restrict__ W2, const float* __restrict__ b2,
              float2* __restrict__ TD, float hstep) {
    __shared__ float rbf[5][64];
    __shared__ float h1[5][128];
    __shared__ float t2[5][128];
    int t = threadIdx.x;
    int k0 = blockIdx.x * 4;

    for (int it = t; it < 5 * 64; it += 256) {
        int kk = it >> 6, m = it & 63;
        float d = (float)(k0 + kk) * hstep;
        float u = (float)m * MU_STEP - d;
        rbf[kk][m] = __expf(-10.f * u * u);
    }
    __syncthreads();
    for (int it = t; it < 5 * 128; it += 256) {
        int kk = it >> 7, f = it & 127;
        float a = b1[f];
#pragma unroll 8
        for (int m = 0; m < 64; ++m)
            a = fmaf(rbf[kk][m], W1[m * 128 + f], a);
        h1[kk][f] = ssp(a);
    }
    __syncthreads();
    for (int it = t; it < 5 * 128; it += 256) {
        int kk = it >> 7, g = it & 127;
        float a = b2[g];
#pragma unroll 8
        for (int f = 0; f < 128; ++f)
            a = fmaf(h1[kk][f], W2[f * 128 + g], a);
        t2[kk][g] = ssp(a);
    }
    __syncthreads();
    for (int it = t; it < 4 * 128; it += 256) {
        int kk = it >> 7, g = it & 127;
        TD[(size_t)(k0 + kk) * 128 + g] = make_float2(t2[kk][g], t2[kk + 1][g] - t2[kk][g]);
    }
}

// Block = (b, i-pair, j-half). 256 thr: wave w owns 24 j's, lane g2 owns g pair
// (2*g2, 2*g2+1). Two atomic contributions per out element (commutative -> det).
__global__ __launch_bounds__(256, 6)
void cfconv_main(const float* __restrict__ X, const float* __restrict__ R,
                 const float* __restrict__ Mask, const float* __restrict__ TD,
                 float* __restrict__ out, int nk, float scale) {
    int blk = blockIdx.x;
    int b = blk & 7;            // XCD round-robin: one batch per XCD
    int r = blk >> 3;           // 0..191
    int jh = r & 1;
    int ip = r >> 1;            // 0..95
    int i0 = ip * 2;
    int tid = threadIdx.x;
    int w = tid >> 6, g2 = tid & 63;

    __shared__ __align__(16) int2 kfl[96][2];   // per j: {k*1024, f} for i0,i1
    __shared__ float part[4][2][128];

    if (tid < 192) {
        int jj = tid >> 1, ii = tid & 1;
        int j = jh * 96 + jj;
        int i = i0 + ii;
        const float* Rb = R + b * 576;
        float dx = Rb[i * 3 + 0] - Rb[j * 3 + 0];
        float dy = Rb[i * 3 + 1] - Rb[j * 3 + 1];
        float dz = Rb[i * 3 + 2] - Rb[j * 3 + 2];
        float d2 = dx * dx + dy * dy + dz * dz;
        float d = d2 > 0.f ? sqrtf(d2) : 0.f;
        float u = d * scale;
        int k = (int)u;
        if (k > nk - 2) k = nk - 2;
        kfl[jj][ii] = make_int2(k << 10, __float_as_int(u - (float)k));
    }
    __syncthreads();

    const char* TDb = (const char*)TD;
    unsigned goff = (unsigned)g2 * 16u;
    const float* Xp = X + (size_t)b * 24576 + (size_t)(jh * 96 + w * 24) * 128 + g2 * 2;
    float a00 = 0.f, a01 = 0.f, a10 = 0.f, a11 = 0.f;   // [i][g elem]

#pragma unroll 6
    for (int e = 0; e < 24; ++e) {
        int4 kk = *(const int4*)&kfl[w * 24 + e][0];    // broadcast read
        float f0 = __int_as_float(kk.y), f1 = __int_as_float(kk.w);
        float4 t0 = *(const float4*)(TDb + (unsigned)kk.x + goff);
        float4 t1 = *(const float4*)(TDb + (unsigned)kk.z + goff);
        float2 x = *(const float2*)(Xp + e * 128);
        a00 = fmaf(fmaf(f0, t0.y, t0.x), x.x, a00);
        a01 = fmaf(fmaf(f0, t0.w, t0.z), x.y, a01);
        a10 = fmaf(fmaf(f1, t1.y, t1.x), x.x, a10);
        a11 = fmaf(fmaf(f1, t1.w, t1.z), x.y, a11);
    }

    part[w][0][g2 * 2] = a00; part[w][0][g2 * 2 + 1] = a01;
    part[w][1][g2 * 2] = a10; part[w][1][g2 * 2 + 1] = a11;
    __syncthreads();
    {
        int ii = tid >> 7, g = tid & 127;
        float v = part[0][ii][g] + part[1][ii][g] + part[2][ii][g] + part[3][ii][g];
        v *= Mask[b * 192 + i0 + ii];
        atomicAdd(&out[((size_t)b * 192 + i0 + ii) * 128 + g], v);
    }
}

extern "C" void kernel_launch(void* const* d_in, const int* in_sizes, int n_in,
                              void* d_out, int out_size, void* d_ws, size_t ws_size,
                              hipStream_t stream) {
    const float* X    = (const float*)d_in[0];
    const float* R    = (const float*)d_in[1];
    const float* Mask = (const float*)d_in[2];
    const float* W1   = (const float*)d_in[3];
    const float* b1   = (const float*)d_in[4];
    const float* W2   = (const float*)d_in[5];
    const float* b2   = (const float*)d_in[6];

    // TD table: nk rows x 128 float2 (1 KB/row) in d_ws. Target nk=4096 (4 MB).
    int nk = 4096;
    size_t maxrows = ws_size / 1024;
    if ((size_t)nk > maxrows) nk = (int)(maxrows & ~(size_t)3);
    if (nk < 8) nk = 8;
    float hstep = 30.0f / (float)(nk - 1);
    float scale = (float)(nk - 1) / 30.0f;
    float2* TD = (float2*)d_ws;

    hipMemsetAsync(d_out, 0, (size_t)out_size * sizeof(float), stream);
    build_td<<<nk / 4, 256, 0, stream>>>(W1, b1, W2, b2, TD, hstep);
    cfconv_main<<<1536, 256, 0, stream>>>(X, R, Mask, (const float*)TD, (float*)d_out, nk, scale);
}

// Round 6
// 39.156 us; speedup vs baseline: 1.1272x; 1.1272x over previous
//
#include <hip/hip_runtime.h>

#define MU_STEP (30.0f / 63.0f)
#define LN2F 0.69314718055994531f

static __device__ __forceinline__ float ssp(float x) {
    // softplus(x) - ln2, stable: max(x,0) + log(1+exp(-|x|)) - ln2
    return fmaxf(x, 0.f) + __logf(1.f + __expf(-fabsf(x))) - LN2F;
}

// Build TD[k][g] = { T[k][g], T[k+1][g]-T[k][g] } (float2 pairs, row=1KB), where
// T[k][g] = ssp(ssp(rbf(k*hstep)@W1+b1)@W2+b2)[g]. Each block computes 5
// consecutive T rows in LDS and emits 4 TD rows.
__global__ __launch_bounds__(256, 4)
void build_td(const float* __restrict__ W1, const float* __restrict__ b1,
              const float* __restrict__ W2, const float* __restrict__ b2,
              float2* __restrict__ TD, float hstep) {
    __shared__ float rbf[5][64];
    __shared__ float h1[5][128];
    __shared__ float t2[5][128];
    int t = threadIdx.x;
    int k0 = blockIdx.x * 4;

    for (int it = t; it < 5 * 64; it += 256) {
        int kk = it >> 6, m = it & 63;
        float d = (float)(k0 + kk) * hstep;
        float u = (float)m * MU_STEP - d;
        rbf[kk][m] = __expf(-10.f * u * u);
    }
    __syncthreads();
    for (int it = t; it < 5 * 128; it += 256) {
        int kk = it >> 7, f = it & 127;
        float a = b1[f];
#pragma unroll 8
        for (int m = 0; m < 64; ++m)
            a = fmaf(rbf[kk][m], W1[m * 128 + f], a);
        h1[kk][f] = ssp(a);
    }
    __syncthreads();
    for (int it = t; it < 5 * 128; it += 256) {
        int kk = it >> 7, g = it & 127;
        float a = b2[g];
#pragma unroll 8
        for (int f = 0; f < 128; ++f)
            a = fmaf(h1[kk][f], W2[f * 128 + g], a);
        t2[kk][g] = ssp(a);
    }
    __syncthreads();
    for (int it = t; it < 4 * 128; it += 256) {
        int kk = it >> 7, g = it & 127;
        TD[(size_t)(k0 + kk) * 128 + g] = make_float2(t2[kk][g], t2[kk + 1][g] - t2[kk][g]);
    }
}

// Block = (b, i-pair), 512 threads / 8 waves; wave w owns j = w*24..w*24+23;
// lane g2 owns g pair (2g2, 2g2+1). Each block exclusively writes 2 out rows:
// no atomics, no output pre-zeroing needed.
__global__ __launch_bounds__(512, 6)
void cfconv_main(const float* __restrict__ X, const float* __restrict__ R,
                 const float* __restrict__ Mask, const float* __restrict__ TD,
                 float* __restrict__ out, int nk, float scale) {
    int blk = blockIdx.x;
    int b = blk & 7;            // XCD round-robin: one batch per XCD
    int ip = blk >> 3;          // 0..95
    int i0 = ip * 2;
    int tid = threadIdx.x;
    int w = tid >> 6, g2 = tid & 63;

    __shared__ __align__(16) int2 kfl[192][2];   // per j: {k*1024, f} for i0,i1
    __shared__ float part[8][2][128];            // 8 KB

    if (tid < 384) {
        int jj = tid >> 1, ii = tid & 1;
        int i = i0 + ii;
        const float* Rb = R + b * 576;
        float dx = Rb[i * 3 + 0] - Rb[jj * 3 + 0];
        float dy = Rb[i * 3 + 1] - Rb[jj * 3 + 1];
        float dz = Rb[i * 3 + 2] - Rb[jj * 3 + 2];
        float d2 = dx * dx + dy * dy + dz * dz;
        float d = d2 > 0.f ? sqrtf(d2) : 0.f;
        float u = d * scale;
        int k = (int)u;
        if (k > nk - 2) k = nk - 2;
        kfl[jj][ii] = make_int2(k << 10, __float_as_int(u - (float)k));
    }
    __syncthreads();

    const char* TDb = (const char*)TD;
    unsigned goff = (unsigned)g2 * 16u;
    const float* Xp = X + (size_t)b * 24576 + (size_t)(w * 24) * 128 + g2 * 2;
    float a00 = 0.f, a01 = 0.f, a10 = 0.f, a11 = 0.f;   // [i][g elem]

#pragma unroll 6
    for (int e = 0; e < 24; ++e) {
        int4 kk = *(const int4*)&kfl[w * 24 + e][0];    // LDS broadcast
        float f0 = __int_as_float(kk.y), f1 = __int_as_float(kk.w);
        float4 t0 = *(const float4*)(TDb + (unsigned)kk.x + goff);
        float4 t1 = *(const float4*)(TDb + (unsigned)kk.z + goff);
        float2 x = *(const float2*)(Xp + e * 128);
        a00 = fmaf(fmaf(f0, t0.y, t0.x), x.x, a00);
        a01 = fmaf(fmaf(f0, t0.w, t0.z), x.y, a01);
        a10 = fmaf(fmaf(f1, t1.y, t1.x), x.x, a10);
        a11 = fmaf(fmaf(f1, t1.w, t1.z), x.y, a11);
    }

    part[w][0][g2 * 2] = a00; part[w][0][g2 * 2 + 1] = a01;
    part[w][1][g2 * 2] = a10; part[w][1][g2 * 2 + 1] = a11;
    __syncthreads();
    if (tid < 256) {
        int ii = tid >> 7, g = tid & 127;
        float v = 0.f;
#pragma unroll
        for (int ww = 0; ww < 8; ++ww) v += part[ww][ii][g];
        v *= Mask[b * 192 + i0 + ii];
        out[((size_t)b * 192 + i0 + ii) * 128 + g] = v;
    }
}

extern "C" void kernel_launch(void* const* d_in, const int* in_sizes, int n_in,
                              void* d_out, int out_size, void* d_ws, size_t ws_size,
                              hipStream_t stream) {
    const float* X    = (const float*)d_in[0];
    const float* R    = (const float*)d_in[1];
    const float* Mask = (const float*)d_in[2];
    const float* W1   = (const float*)d_in[3];
    const float* b1   = (const float*)d_in[4];
    const float* W2   = (const float*)d_in[5];
    const float* b2   = (const float*)d_in[6];

    // TD table: nk rows x 128 float2 (1 KB/row) in d_ws. Target nk=4096 (4 MB).
    int nk = 4096;
    size_t maxrows = ws_size / 1024;
    if ((size_t)nk > maxrows) nk = (int)(maxrows & ~(size_t)3);
    if (nk < 8) nk = 8;
    float hstep = 30.0f / (float)(nk - 1);
    float scale = (float)(nk - 1) / 30.0f;
    float2* TD = (float2*)d_ws;

    build_td<<<nk / 4, 256, 0, stream>>>(W1, b1, W2, b2, TD, hstep);
    cfconv_main<<<768, 512, 0, stream>>>(X, R, Mask, (const float*)TD, (float*)d_out, nk, scale);
}

// Round 7
// 38.282 us; speedup vs baseline: 1.1530x; 1.0228x over previous
//
#include <hip/hip_runtime.h>
#include <hip/hip_fp16.h>

#define MU_STEP (30.0f / 63.0f)
#define LN2F 0.69314718055994531f

typedef unsigned u32;

static __device__ __forceinline__ float ssp(float x) {
    // softplus(x) - ln2, stable: max(x,0) + log(1+exp(-|x|)) - ln2
    return fmaxf(x, 0.f) + __logf(1.f + __expf(-fabsf(x))) - LN2F;
}

// Build fp16 TD table: row k, g-pair g2 holds {half2 value, half2 delta}:
//   value = (T[k][2g2], T[k][2g2+1]), delta = T[k+1]-T[k] elementwise,
// T[k][g] = ssp(ssp(rbf(k*hstep)@W1+b1)@W2+b2)[g]. Row = 64*8B = 512B.
__global__ __launch_bounds__(256, 4)
void build_td(const float* __restrict__ W1, const float* __restrict__ b1,
              const float* __restrict__ W2, const float* __restrict__ b2,
              uint2* __restrict__ TD, float hstep) {
    __shared__ float rbf[5][64];
    __shared__ float h1[5][128];
    __shared__ float t2[5][128];
    int t = threadIdx.x;
    int k0 = blockIdx.x * 4;

    for (int it = t; it < 5 * 64; it += 256) {
        int kk = it >> 6, m = it & 63;
        float d = (float)(k0 + kk) * hstep;
        float u = (float)m * MU_STEP - d;
        rbf[kk][m] = __expf(-10.f * u * u);
    }
    __syncthreads();
    for (int it = t; it < 5 * 128; it += 256) {
        int kk = it >> 7, f = it & 127;
        float a = b1[f];
#pragma unroll 8
        for (int m = 0; m < 64; ++m)
            a = fmaf(rbf[kk][m], W1[m * 128 + f], a);
        h1[kk][f] = ssp(a);
    }
    __syncthreads();
    for (int it = t; it < 5 * 128; it += 256) {
        int kk = it >> 7, g = it & 127;
        float a = b2[g];
#pragma unroll 8
        for (int f = 0; f < 128; ++f)
            a = fmaf(h1[kk][f], W2[f * 128 + g], a);
        t2[kk][g] = ssp(a);
    }
    __syncthreads();
    for (int it = t; it < 4 * 64; it += 256) {
        int kk = it >> 6, g2 = it & 63;
        float v0 = t2[kk][2 * g2], v1 = t2[kk][2 * g2 + 1];
        float d0 = t2[kk + 1][2 * g2] - v0, d1 = t2[kk + 1][2 * g2 + 1] - v1;
        __half2 vh = __floats2half2_rn(v0, v1);
        __half2 dh = __floats2half2_rn(d0, d1);
        uint2 wo;
        wo.x = __builtin_bit_cast(u32, vh);
        wo.y = __builtin_bit_cast(u32, dh);
        TD[(size_t)(k0 + kk) * 64 + g2] = wo;
    }
}

// Block = (b, i-pair), 256 thr / 4 waves; wave w owns j = w*48..w*48+47;
// lane g2 owns g pair (2g2, 2g2+1). Exclusive output writes, no atomics.
__global__ __launch_bounds__(256, 6)
void cfconv_main(const float* __restrict__ X, const float* __restrict__ R,
                 const float* __restrict__ Mask, const uint2* __restrict__ TD,
                 float* __restrict__ out, int nk, float scale) {
    int blk = blockIdx.x;
    int b = blk & 7;            // XCD round-robin: one batch per XCD
    int ip = blk >> 3;          // 0..95
    int i0 = ip * 2;
    int tid = threadIdx.x;
    int w = tid >> 6, g2 = tid & 63;

    __shared__ __align__(16) int2 kfl[192][2];   // per j: {k*512, half2(f) bits} x {i0,i1}
    __shared__ float part[4][2][128];

    for (int idx = tid; idx < 384; idx += 256) {
        int jj = idx >> 1, ii = idx & 1;
        int i = i0 + ii;
        const float* Rb = R + b * 576;
        float dx = Rb[i * 3 + 0] - Rb[jj * 3 + 0];
        float dy = Rb[i * 3 + 1] - Rb[jj * 3 + 1];
        float dz = Rb[i * 3 + 2] - Rb[jj * 3 + 2];
        float d2 = dx * dx + dy * dy + dz * dz;
        float d = d2 > 0.f ? sqrtf(d2) : 0.f;
        float u = d * scale;
        int k = (int)u;
        if (k > nk - 2) k = nk - 2;
        __half2 fh = __float2half2_rn(u - (float)k);
        kfl[jj][ii] = make_int2(k << 9, (int)__builtin_bit_cast(u32, fh));
    }
    __syncthreads();

    const char* TDb = (const char*)TD;
    unsigned goff = (unsigned)g2 * 8u;
    const float* Xp = X + (size_t)b * 24576 + (size_t)(w * 48) * 128 + g2 * 2;
    float a00 = 0.f, a01 = 0.f, a10 = 0.f, a11 = 0.f;   // [i][g elem]

#pragma unroll 8
    for (int e = 0; e < 48; ++e) {
        int4 kk = *(const int4*)&kfl[w * 48 + e][0];    // LDS broadcast
        uint2 t0 = *(const uint2*)(TDb + (unsigned)kk.x + goff);
        uint2 t1 = *(const uint2*)(TDb + (unsigned)kk.z + goff);
        float2 x = *(const float2*)(Xp + e * 128);
        __half2 p0 = __hfma2(__builtin_bit_cast(__half2, kk.y),
                             __builtin_bit_cast(__half2, t0.y),
                             __builtin_bit_cast(__half2, t0.x));
        __half2 p1 = __hfma2(__builtin_bit_cast(__half2, kk.w),
                             __builtin_bit_cast(__half2, t1.y),
                             __builtin_bit_cast(__half2, t1.x));
        float2 q0 = __half22float2(p0);
        float2 q1 = __half22float2(p1);
        a00 = fmaf(q0.x, x.x, a00);
        a01 = fmaf(q0.y, x.y, a01);
        a10 = fmaf(q1.x, x.x, a10);
        a11 = fmaf(q1.y, x.y, a11);
    }

    part[w][0][g2 * 2] = a00; part[w][0][g2 * 2 + 1] = a01;
    part[w][1][g2 * 2] = a10; part[w][1][g2 * 2 + 1] = a11;
    __syncthreads();
    {
        int ii = tid >> 7, g = tid & 127;
        float v = part[0][ii][g] + part[1][ii][g] + part[2][ii][g] + part[3][ii][g];
        v *= Mask[b * 192 + i0 + ii];
        out[((size_t)b * 192 + i0 + ii) * 128 + g] = v;
    }
}

extern "C" void kernel_launch(void* const* d_in, const int* in_sizes, int n_in,
                              void* d_out, int out_size, void* d_ws, size_t ws_size,
                              hipStream_t stream) {
    const float* X    = (const float*)d_in[0];
    const float* R    = (const float*)d_in[1];
    const float* Mask = (const float*)d_in[2];
    const float* W1   = (const float*)d_in[3];
    const float* b1   = (const float*)d_in[4];
    const float* W2   = (const float*)d_in[5];
    const float* b2   = (const float*)d_in[6];

    // fp16 TD table: nk rows x 512 B in d_ws. Target nk=4096 (2 MB).
    int nk = 4096;
    size_t maxrows = ws_size / 512;
    if ((size_t)nk > maxrows) nk = (int)(maxrows & ~(size_t)3);
    if (nk < 8) nk = 8;
    float hstep = 30.0f / (float)(nk - 1);
    float scale = (float)(nk - 1) / 30.0f;
    uint2* TD = (uint2*)d_ws;

    build_td<<<nk / 4, 256, 0, stream>>>(W1, b1, W2, b2, TD, hstep);
    cfconv_main<<<768, 256, 0, stream>>>(X, R, Mask, TD, (float*)d_out, nk, scale);
}

// Round 8
// 35.340 us; speedup vs baseline: 1.2490x; 1.0833x over previous
//
#include <hip/hip_runtime.h>
#include <hip/hip_fp16.h>

#define MU_STEP (30.0f / 63.0f)
#define LN2F 0.69314718055994531f

typedef unsigned u32;

static __device__ __forceinline__ float ssp(float x) {
    // softplus(x) - ln2, stable: max(x,0) + log(1+exp(-|x|)) - ln2
    return fmaxf(x, 0.f) + __logf(1.f + __expf(-fabsf(x))) - LN2F;
}

// build_td v2: 16 TD rows per block (17 T rows incl. boundary). Thread t
// owns output column g = t&127 and kk-pair set q = (t>>7), q+2, ... ; W1/W2
// columns held in REGISTERS (no global traffic inside the fma chains);
// rbf^T / h1^T tiles in LDS, read as wave-uniform float2 broadcasts.
// Summation order (m asc, f asc, single accumulator from bias) matches the
// previous build exactly -> bit-identical table.
__global__ __launch_bounds__(256, 1)
void build_td(const float* __restrict__ W1, const float* __restrict__ b1,
              const float* __restrict__ W2, const float* __restrict__ b2,
              uint2* __restrict__ TD, float hstep) {
    __shared__ float rbfT[64][20];   // [m][kk], kk 0..16 valid, pad to 20
    __shared__ float h1T[128][20];   // [f][kk]
    __shared__ float t2[17][128];    // [kk][g]
    int t = threadIdx.x;
    int k0 = blockIdx.x * 16;
    int g = t & 127, kp = t >> 7;

    // W1 column into registers (coalesced across lanes; issued early)
    float w1c[64];
#pragma unroll
    for (int m = 0; m < 64; ++m) w1c[m] = W1[m * 128 + g];
    float b1g = b1[g], b2g = b2[g];

    // rbf^T tile: 17 rows x 64 mu
    for (int it = t; it < 17 * 64; it += 256) {
        int kk = it >> 6, m = it & 63;
        float d = (float)(k0 + kk) * hstep;
        float u = (float)m * MU_STEP - d;
        rbfT[m][kk] = __expf(-10.f * u * u);
    }
    __syncthreads();

    // GEMM1 + ssp -> h1T (kk-pairs {2q, 2q+1}; q=8 is the singleton kk=16)
    for (int q = kp; q < 9; q += 2) {
        int kk = q * 2;
        float a0 = b1g, a1 = b1g;
#pragma unroll
        for (int m = 0; m < 64; ++m) {
            float2 rr = *(const float2*)&rbfT[m][kk];   // uniform: LDS broadcast
            a0 = fmaf(rr.x, w1c[m], a0);
            a1 = fmaf(rr.y, w1c[m], a1);
        }
        h1T[g][kk] = ssp(a0);
        if (q < 8) h1T[g][kk + 1] = ssp(a1);
    }

    // W2 column into registers (after GEMM1 to cap live VGPRs)
    float w2c[128];
#pragma unroll
    for (int f = 0; f < 128; ++f) w2c[f] = W2[f * 128 + g];
    __syncthreads();

    // GEMM2 + ssp -> t2
    for (int q = kp; q < 9; q += 2) {
        int kk = q * 2;
        float a0 = b2g, a1 = b2g;
#pragma unroll
        for (int f = 0; f < 128; ++f) {
            float2 hh = *(const float2*)&h1T[f][kk];    // uniform: LDS broadcast
            a0 = fmaf(hh.x, w2c[f], a0);
            a1 = fmaf(hh.y, w2c[f], a1);
        }
        t2[kk][g] = ssp(a0);
        if (q < 8) t2[kk + 1][g] = ssp(a1);
    }
    __syncthreads();

    // Pack fp16 TD rows: {half2 value, half2 delta} per g-pair
    for (int it = t; it < 16 * 64; it += 256) {
        int kk = it >> 6, g2 = it & 63;
        float v0 = t2[kk][2 * g2], v1 = t2[kk][2 * g2 + 1];
        float d0 = t2[kk + 1][2 * g2] - v0, d1 = t2[kk + 1][2 * g2 + 1] - v1;
        __half2 vh = __floats2half2_rn(v0, v1);
        __half2 dh = __floats2half2_rn(d0, d1);
        uint2 wo;
        wo.x = __builtin_bit_cast(u32, vh);
        wo.y = __builtin_bit_cast(u32, dh);
        TD[(size_t)(k0 + kk) * 64 + g2] = wo;
    }
}

// Main kernel: UNCHANGED from round 7 (isolating the build_td change).
__global__ __launch_bounds__(256, 6)
void cfconv_main(const float* __restrict__ X, const float* __restrict__ R,
                 const float* __restrict__ Mask, const uint2* __restrict__ TD,
                 float* __restrict__ out, int nk, float scale) {
    int blk = blockIdx.x;
    int b = blk & 7;            // XCD round-robin: one batch per XCD
    int ip = blk >> 3;          // 0..95
    int i0 = ip * 2;
    int tid = threadIdx.x;
    int w = tid >> 6, g2 = tid & 63;

    __shared__ __align__(16) int2 kfl[192][2];   // per j: {k*512, half2(f) bits} x {i0,i1}
    __shared__ float part[4][2][128];

    for (int idx = tid; idx < 384; idx += 256) {
        int jj = idx >> 1, ii = idx & 1;
        int i = i0 + ii;
        const float* Rb = R + b * 576;
        float dx = Rb[i * 3 + 0] - Rb[jj * 3 + 0];
        float dy = Rb[i * 3 + 1] - Rb[jj * 3 + 1];
        float dz = Rb[i * 3 + 2] - Rb[jj * 3 + 2];
        float d2 = dx * dx + dy * dy + dz * dz;
        float d = d2 > 0.f ? sqrtf(d2) : 0.f;
        float u = d * scale;
        int k = (int)u;
        if (k > nk - 2) k = nk - 2;
        __half2 fh = __float2half2_rn(u - (float)k);
        kfl[jj][ii] = make_int2(k << 9, (int)__builtin_bit_cast(u32, fh));
    }
    __syncthreads();

    const char* TDb = (const char*)TD;
    unsigned goff = (unsigned)g2 * 8u;
    const float* Xp = X + (size_t)b * 24576 + (size_t)(w * 48) * 128 + g2 * 2;
    float a00 = 0.f, a01 = 0.f, a10 = 0.f, a11 = 0.f;   // [i][g elem]

#pragma unroll 8
    for (int e = 0; e < 48; ++e) {
        int4 kk = *(const int4*)&kfl[w * 48 + e][0];    // LDS broadcast
        uint2 t0 = *(const uint2*)(TDb + (unsigned)kk.x + goff);
        uint2 t1 = *(const uint2*)(TDb + (unsigned)kk.z + goff);
        float2 x = *(const float2*)(Xp + e * 128);
        __half2 p0 = __hfma2(__builtin_bit_cast(__half2, kk.y),
                             __builtin_bit_cast(__half2, t0.y),
                             __builtin_bit_cast(__half2, t0.x));
        __half2 p1 = __hfma2(__builtin_bit_cast(__half2, kk.w),
                             __builtin_bit_cast(__half2, t1.y),
                             __builtin_bit_cast(__half2, t1.x));
        float2 q0 = __half22float2(p0);
        float2 q1 = __half22float2(p1);
        a00 = fmaf(q0.x, x.x, a00);
        a01 = fmaf(q0.y, x.y, a01);
        a10 = fmaf(q1.x, x.x, a10);
        a11 = fmaf(q1.y, x.y, a11);
    }

    part[w][0][g2 * 2] = a00; part[w][0][g2 * 2 + 1] = a01;
    part[w][1][g2 * 2] = a10; part[w][1][g2 * 2 + 1] = a11;
    __syncthreads();
    {
        int ii = tid >> 7, g = tid & 127;
        float v = part[0][ii][g] + part[1][ii][g] + part[2][ii][g] + part[3][ii][g];
        v *= Mask[b * 192 + i0 + ii];
        out[((size_t)b * 192 + i0 + ii) * 128 + g] = v;
    }
}

extern "C" void kernel_launch(void* const* d_in, const int* in_sizes, int n_in,
                              void* d_out, int out_size, void* d_ws, size_t ws_size,
                              hipStream_t stream) {
    const float* X    = (const float*)d_in[0];
    const float* R    = (const float*)d_in[1];
    const float* Mask = (const float*)d_in[2];
    const float* W1   = (const float*)d_in[3];
    const float* b1   = (const float*)d_in[4];
    const float* W2   = (const float*)d_in[5];
    const float* b2   = (const float*)d_in[6];

    // fp16 TD table: nk rows x 512 B in d_ws. nk must be a multiple of 16.
    int nk = 4096;
    size_t maxrows = ws_size / 512;
    if ((size_t)nk > maxrows) nk = (int)(maxrows & ~(size_t)15);
    if (nk < 16) nk = 16;
    float hstep = 30.0f / (float)(nk - 1);
    float scale = (float)(nk - 1) / 30.0f;
    uint2* TD = (uint2*)d_ws;

    build_td<<<nk / 16, 256, 0, stream>>>(W1, b1, W2, b2, TD, hstep);
    cfconv_main<<<768, 256, 0, stream>>>(X, R, Mask, TD, (float*)d_out, nk, scale);
}